// Round 11
// baseline (355.840 us; speedup 1.0000x reference)
//
#include <hip/hip_runtime.h>
#include <hip/hip_bf16.h>
#include <stdint.h>

#define EE 131072
#define DDEG 64

typedef __bf16 bf16_t;
typedef bf16_t bf16x8 __attribute__((ext_vector_type(8)));
typedef float floatx4 __attribute__((ext_vector_type(4)));

// XOR-swizzled LDS addressing: row-major [64][256] bf16, bits 3..5 of the
// k-index xor'd with (row&7) -> b128 reads/writes across rows are bank-even.
#define SWZ(row, k) (((row) << 8) + ((k) ^ (((row) & 7) << 3)))

// ---------------- prep: CN | transpose | Mt | cvec | T2 | x->bf16 ------------
// (r9-verified) grid: [0,2048) CN, [2048,2112) transpose, [2112,2368) Mt,
// [2368,2624) cvec, [2624,3136) T2, [3136,3136+6250) xb conversion.
__global__ __launch_bounds__(256)
void prep_kernel(const float* __restrict__ x, bf16_t* __restrict__ xb,
                 const int* __restrict__ tar, const int* __restrict__ nbr,
                 int* __restrict__ xcnbuf,
                 const float* __restrict__ ij_w1, bf16_t* __restrict__ Wt1,
                 const float* __restrict__ w2, const float* __restrict__ lw1,
                 bf16_t* __restrict__ Mt,
                 const float* __restrict__ b2, const float* __restrict__ lb1,
                 float* __restrict__ cvec,
                 const float* __restrict__ cw1, const float* __restrict__ cb1,
                 const float* __restrict__ cw2, const float* __restrict__ cb2,
                 const float* __restrict__ cw3, const float* __restrict__ cb3,
                 const float* __restrict__ beta, float* __restrict__ T2) {
    __shared__ __align__(16) char arena[33792];
    const int bid = blockIdx.x;
    const int t = threadIdx.x;

    if (bid >= 3136) {
        // ---- xb = bf16(x), 16 elements per thread ----
        size_t base = (size_t)(bid - 3136) * 4096 + (size_t)t * 16;
        float4 a0 = *(const float4*)(x + base);
        float4 a1 = *(const float4*)(x + base + 4);
        float4 a2 = *(const float4*)(x + base + 8);
        float4 a3 = *(const float4*)(x + base + 12);
        bf16x8 o0, o1;
        o0[0] = (bf16_t)a0.x; o0[1] = (bf16_t)a0.y; o0[2] = (bf16_t)a0.z; o0[3] = (bf16_t)a0.w;
        o0[4] = (bf16_t)a1.x; o0[5] = (bf16_t)a1.y; o0[6] = (bf16_t)a1.z; o0[7] = (bf16_t)a1.w;
        o1[0] = (bf16_t)a2.x; o1[1] = (bf16_t)a2.y; o1[2] = (bf16_t)a2.z; o1[3] = (bf16_t)a2.w;
        o1[4] = (bf16_t)a3.x; o1[5] = (bf16_t)a3.y; o1[6] = (bf16_t)a3.z; o1[7] = (bf16_t)a3.w;
        *(bf16x8*)(xb + base)     = o0;
        *(bf16x8*)(xb + base + 8) = o1;
        return;
    }

    if (bid < 2048) {
        // ---- CN: per-wave 16 edges, sorted-list pair count via binary search.
        const int lane = t & 63;
        const int wcn  = t >> 6;
        const int e0   = bid * 64 + wcn * 16;
        int va[16], vb[16];
        #pragma unroll
        for (int i = 0; i < 16; ++i) {
            int e = e0 + i;
            int s = __builtin_amdgcn_readfirstlane(tar[e]);
            int d = __builtin_amdgcn_readfirstlane(tar[EE + e]);
            va[i] = nbr[(size_t)s * DDEG + lane];
            vb[i] = nbr[(size_t)d * DDEG + lane];
        }
        #pragma unroll
        for (int p = 0; p < 8; ++p) {
            int cpk = 0;
            #pragma unroll
            for (int h = 0; h < 2; ++h) {
                int i = p * 2 + h;
                int lo = 0, hi = 0;
                #pragma unroll
                for (int st = 32; st; st >>= 1) {
                    int bl = __shfl(vb[i], lo + st - 1, 64);
                    int bh = __shfl(vb[i], hi + st - 1, 64);
                    lo += (bl < va[i]) ? st : 0;
                    hi += (bh <= va[i]) ? st : 0;
                }
                int b63 = __shfl(vb[i], 63, 64);      // count==64 correction
                lo += (b63 < va[i]) ? 1 : 0;
                hi += (b63 <= va[i]) ? 1 : 0;
                cpk += (hi - lo) << (16 * h);
            }
            #pragma unroll
            for (int off = 32; off; off >>= 1) cpk += __shfl_xor(cpk, off, 64);
            if (lane == 0) {
                int c0 = cpk & 0xffff, c1 = (int)((unsigned)cpk >> 16);
                xcnbuf[e0 + p * 2]     = c0 < 511 ? c0 : 511;
                xcnbuf[e0 + p * 2 + 1] = c1 < 511 ? c1 : 511;
            }
        }
        return;
    }

    const int b2id = bid - 2048;
    if (b2id < 64) {
        // ---- transpose ij_w1 fp32[k][n] -> bf16 Wt1[n][k] ----
        float (*tile)[33] = (float (*)[33])arena;
        int bx = b2id & 7, by = b2id >> 3;
        int tx = t & 31, ty = t >> 5;
        #pragma unroll
        for (int r = 0; r < 32; r += 8)
            tile[ty + r][tx] = ij_w1[(by * 32 + ty + r) * 256 + bx * 32 + tx];
        __syncthreads();
        #pragma unroll
        for (int r = 0; r < 32; r += 8)
            Wt1[(bx * 32 + ty + r) * 256 + by * 32 + tx] = (bf16_t)tile[tx][ty + r];
    } else if (b2id < 320) {
        // ---- Mt[b][a] = sum_c ij_w2[a][c] * lin_w1[c][b] (bf16 [n][k]) ----
        float (*S)[33] = (float (*)[33])arena;
        int b = b2id - 64;
        int cc = t & 31, abase = t >> 5;
        float acc = 0.f;
        for (int c0 = 0; c0 < 256; c0 += 32) {
            __syncthreads();
            #pragma unroll
            for (int r = 0; r < 32; ++r) {
                int a = r * 8 + abase;
                S[a][cc] = w2[a * 256 + c0 + cc];
            }
            __syncthreads();
            #pragma unroll 8
            for (int c2 = 0; c2 < 32; ++c2) {
                float wv = lw1[(c0 + c2) * 256 + b];   // uniform -> scalar
                acc += S[t][c2] * wv;
            }
        }
        Mt[(size_t)b * 256 + t] = (bf16_t)acc;
    } else if (b2id < 576) {
        // ---- cvec[b] = ij_b2 @ lin_w1 + lin_b1 ----
        float* red = (float*)arena;
        int b = b2id - 320;
        red[t] = b2[t] * lw1[t * 256 + b];
        __syncthreads();
        for (int s = 128; s > 0; s >>= 1) {
            if (t < s) red[t] += red[t + s];
            __syncthreads();
        }
        if (t == 0) cvec[b] = red[0] + lb1[b];
    } else {
        // ---- T2[v] = (cn_mlp(v) * beta) @ lin_w1, v = 0..511 ----
        float* t1 = (float*)arena;
        float* t2 = (float*)(arena + 1024);
        float* t3 = (float*)(arena + 2048);
        int v = b2id - 576;
        float fv = (float)v;
        t1[t] = fmaxf(fv * cw1[t] + cb1[t], 0.f);
        __syncthreads();
        float s = cb2[t];
        for (int k = 0; k < 256; ++k) s += t1[k] * cw2[k * 256 + t];
        t2[t] = fmaxf(s, 0.f);
        __syncthreads();
        s = cb3[t];
        for (int k = 0; k < 256; ++k) s += t2[k] * cw3[k * 256 + t];
        t3[t] = s * beta[0];
        __syncthreads();
        s = 0.f;
        for (int k = 0; k < 256; ++k) s += t3[k] * lw1[k * 256 + t];
        T2[(size_t)v * 256 + t] = s;
    }
}

// ---------------- fused: 8-wave (512t), 64-edge tile, acc split 2x4 ----------
// Per-wave acc[2][4] = 32 AGPRs (vs 64 at 4-wave) -> unified demand ~80-100
// -> 4-6 waves/SIMD vs 3. Waves: wr = rows/2, wcN = cols/4; B fragments
// duplicated across wr (cheap, L2-hot). bf16 xb staging (r9-proven path).
__global__ __launch_bounds__(512, 4)
void fused_kernel(const bf16_t* __restrict__ xb, const int* __restrict__ tar,
                  const bf16_t* __restrict__ Wt1, const float* __restrict__ b1,
                  const bf16_t* __restrict__ Mt, const float* __restrict__ cvec,
                  const float* __restrict__ T2, const int* __restrict__ xcnbuf,
                  const float* __restrict__ w2, const float* __restrict__ b2s,
                  float* __restrict__ out) {
    __shared__ __align__(16) bf16_t X[64 * 256];   // A tile -> g tile -> partials

    const int tid  = threadIdx.x;
    const int lane = tid & 63;
    const int wave = tid >> 6;          // 0..7
    const int wr   = wave >> 2;         // row half 0..1
    const int wcN  = wave & 3;          // col quarter 0..3
    const int quad = lane >> 4;
    const int l16  = lane & 15;
    const int e0   = blockIdx.x * 64;

    // ---- stage A = bf16(xi * xj), 8 threads/row, swizzled writes ----
    {
        const int srow   = tid >> 3;
        const int skbase = (tid & 7) * 8;
        int e = e0 + srow;
        const bf16_t* xi = xb + (size_t)tar[e] * 256 + skbase;
        const bf16_t* xj = xb + (size_t)tar[EE + e] * 256 + skbase;
        bf16x8 ui[4], vj[4];
        #pragma unroll
        for (int kc = 0; kc < 4; ++kc) {
            ui[kc] = *(const bf16x8*)(xi + kc * 64);
            vj[kc] = *(const bf16x8*)(xj + kc * 64);
        }
        #pragma unroll
        for (int kc = 0; kc < 4; ++kc) {
            bf16x8 p;
            #pragma unroll
            for (int m = 0; m < 8; ++m)
                p[m] = (bf16_t)((float)ui[kc][m] * (float)vj[kc][m]);
            *(bf16x8*)&X[SWZ(srow, kc * 64 + skbase)] = p;
        }
    }

    floatx4 acc[2][4];
    #pragma unroll
    for (int i = 0; i < 2; ++i)
        #pragma unroll
        for (int j = 0; j < 4; ++j)
            acc[i][j] = (floatx4){0.f, 0.f, 0.f, 0.f};

    __syncthreads();   // barrier 1: A staged

    // ---- GEMM1: A from LDS (swizzled), B direct from global (L2-hot) ----
    #pragma unroll 2
    for (int kc = 0; kc < 8; ++kc) {
        const int k0 = kc * 32 + quad * 8;
        bf16x8 af[2], bfr[4];
        #pragma unroll
        for (int j = 0; j < 4; ++j)
            bfr[j] = *(const bf16x8*)(Wt1 + (size_t)(wcN * 64 + j * 16 + l16) * 256 + k0);
        #pragma unroll
        for (int i = 0; i < 2; ++i)
            af[i] = *(const bf16x8*)(&X[SWZ(wr * 32 + i * 16 + l16, k0)]);
        #pragma unroll
        for (int i = 0; i < 2; ++i)
            #pragma unroll
            for (int j = 0; j < 4; ++j)
                acc[i][j] = __builtin_amdgcn_mfma_f32_16x16x32_bf16(
                                af[i], bfr[j], acc[i][j], 0, 0, 0);
    }

    __syncthreads();   // barrier 2: all A reads done, X reusable for g

    // ---- epilogue 1: g tile -> X (bf16, swizzled) ----
    #pragma unroll
    for (int j = 0; j < 4; ++j) {
        int col  = wcN * 64 + j * 16 + l16;
        float bv = b1[col];
        #pragma unroll
        for (int i = 0; i < 2; ++i)
            #pragma unroll
            for (int r = 0; r < 4; ++r) {
                int row = wr * 32 + i * 16 + quad * 4 + r;
                X[SWZ(row, col)] = (bf16_t)fmaxf(acc[i][j][r] + bv, 0.f);
            }
    }
    #pragma unroll
    for (int i = 0; i < 2; ++i)
        #pragma unroll
        for (int j = 0; j < 4; ++j)
            acc[i][j] = (floatx4){0.f, 0.f, 0.f, 0.f};

    __syncthreads();   // barrier 3: g visible

    // ---- GEMM2: g @ M; A from LDS (swizzled), B direct from global ----
    #pragma unroll 2
    for (int kc = 0; kc < 8; ++kc) {
        const int k0 = kc * 32 + quad * 8;
        bf16x8 af[2], bfr[4];
        #pragma unroll
        for (int j = 0; j < 4; ++j)
            bfr[j] = *(const bf16x8*)(Mt + (size_t)(wcN * 64 + j * 16 + l16) * 256 + k0);
        #pragma unroll
        for (int i = 0; i < 2; ++i)
            af[i] = *(const bf16x8*)(&X[SWZ(wr * 32 + i * 16 + l16, k0)]);
        #pragma unroll
        for (int i = 0; i < 2; ++i)
            #pragma unroll
            for (int j = 0; j < 4; ++j)
                acc[i][j] = __builtin_amdgcn_mfma_f32_16x16x32_bf16(
                                af[i], bfr[j], acc[i][j], 0, 0, 0);
    }

    // ---- final epilogue: +cvec +T2[xcn], relu, dot w2, row-reduce ----
    int xv[8];
    #pragma unroll
    for (int i = 0; i < 2; ++i)
        #pragma unroll
        for (int r = 0; r < 4; ++r)
            xv[i * 4 + r] = xcnbuf[e0 + wr * 32 + i * 16 + quad * 4 + r];  // L2-hot

    float pr[8];
    #pragma unroll
    for (int t = 0; t < 8; ++t) pr[t] = 0.f;
    #pragma unroll
    for (int j = 0; j < 4; ++j) {
        int col  = wcN * 64 + j * 16 + l16;
        float cv = cvec[col];
        float wv = w2[col];
        #pragma unroll
        for (int i = 0; i < 2; ++i)
            #pragma unroll
            for (int r = 0; r < 4; ++r) {
                float t2v = T2[(size_t)xv[i * 4 + r] * 256 + col];
                float v = fmaxf(acc[i][j][r] + cv + t2v, 0.f);
                pr[i * 4 + r] += v * wv;
            }
    }
    #pragma unroll
    for (int off = 1; off < 16; off <<= 1)
        #pragma unroll
        for (int t = 0; t < 8; ++t)
            pr[t] += __shfl_xor(pr[t], off, 64);

    __syncthreads();   // barrier 4: all GEMM2 X-reads done, X reusable
    float* red = (float*)X;             // [4 col-groups][64 rows] partials
    if (l16 == 0) {
        #pragma unroll
        for (int i = 0; i < 2; ++i)
            #pragma unroll
            for (int r = 0; r < 4; ++r)
                red[wcN * 64 + wr * 32 + i * 16 + quad * 4 + r] = pr[i * 4 + r];
    }
    __syncthreads();   // barrier 5: partials visible
    if (tid < 64)
        out[e0 + tid] = red[tid] + red[64 + tid] + red[128 + tid]
                      + red[192 + tid] + b2s[0];
}

extern "C" void kernel_launch(void* const* d_in, const int* in_sizes, int n_in,
                              void* d_out, int out_size, void* d_ws, size_t ws_size,
                              hipStream_t stream) {
    const float* x      = (const float*)d_in[0];
    const int*   nbr    = (const int*)  d_in[1];
    const int*   tar    = (const int*)  d_in[2];
    const float* beta   = (const float*)d_in[3];
    const float* cn_w1  = (const float*)d_in[4];
    const float* cn_b1  = (const float*)d_in[5];
    const float* cn_w2  = (const float*)d_in[6];
    const float* cn_b2  = (const float*)d_in[7];
    const float* cn_w3  = (const float*)d_in[8];
    const float* cn_b3  = (const float*)d_in[9];
    const float* ij_w1  = (const float*)d_in[10];
    const float* ij_b1  = (const float*)d_in[11];
    const float* ij_w2  = (const float*)d_in[12];
    const float* ij_b2  = (const float*)d_in[13];
    const float* lin_w1 = (const float*)d_in[14];
    const float* lin_b1 = (const float*)d_in[15];
    const float* lin_w2 = (const float*)d_in[16];
    const float* lin_b2 = (const float*)d_in[17];

    // Workspace layout: EXACT r0-r3 proven footprint (52,512,768 bytes).
    char* ws = (char*)d_ws;
    float*  T2     = (float*) (ws + 0);        // 512*256*4  = 524288
    int*    xcnbuf = (int*)   (ws + 524288);   // E*4        = 524288
    bf16_t* Wt1    = (bf16_t*)(ws + 1048576);  // 256*256*2  = 131072
    bf16_t* Mt     = (bf16_t*)(ws + 1179648);  // 256*256*2  = 131072
    float*  cvec   = (float*) (ws + 1310720);  // 256*4 -> pad to 1312768
    bf16_t* xb     = (bf16_t*)(ws + 1312768);  // 100000*256*2 = 51.2 MB

    prep_kernel<<<3136 + 6250, 256, 0, stream>>>(
        x, xb, tar, nbr, xcnbuf,
        ij_w1, Wt1, ij_w2, lin_w1, Mt,
        ij_b2, lin_b1, cvec,
        cn_w1, cn_b1, cn_w2, cn_b2, cn_w3, cn_b3, beta, T2);
    fused_kernel<<<EE / 64, 512, 0, stream>>>(xb, tar, Wt1, ij_b1, Mt, cvec,
                                              T2, xcnbuf, lin_w2, lin_b2,
                                              (float*)d_out);
}

// Round 12
// 312.095 us; speedup vs baseline: 1.1402x; 1.1402x over previous
//
#include <hip/hip_runtime.h>
#include <hip/hip_bf16.h>
#include <stdint.h>

#define EE 131072
#define DDEG 64

typedef __bf16 bf16_t;
typedef bf16_t bf16x8 __attribute__((ext_vector_type(8)));
typedef float floatx4 __attribute__((ext_vector_type(4)));

// XOR-swizzled LDS addressing: row-major [64][256] bf16, bits 3..5 of the
// k-index xor'd with (row&7) -> b128 reads/writes across rows are bank-even.
#define SWZ(row, k) (((row) << 8) + ((k) ^ (((row) & 7) << 3)))

// ---------------- prep: transpose | Mt | cvec | T2 v=0..511 | x->bf16 --------
// grid: [0,64) transpose, [64,320) Mt, [320,576) cvec, [576,1088) T2,
//       [1088,1088+6250) xb conversion.
__global__ __launch_bounds__(256)
void prep_kernel(const float* __restrict__ x, bf16_t* __restrict__ xb,
                 const float* __restrict__ ij_w1, bf16_t* __restrict__ Wt1,
                 const float* __restrict__ w2, const float* __restrict__ lw1,
                 bf16_t* __restrict__ Mt,
                 const float* __restrict__ b2, const float* __restrict__ lb1,
                 float* __restrict__ cvec,
                 const float* __restrict__ cw1, const float* __restrict__ cb1,
                 const float* __restrict__ cw2, const float* __restrict__ cb2,
                 const float* __restrict__ cw3, const float* __restrict__ cb3,
                 const float* __restrict__ beta, float* __restrict__ T2) {
    __shared__ __align__(16) char arena[33792];
    const int bid = blockIdx.x;
    const int t = threadIdx.x;

    if (bid >= 1088) {
        // ---- xb = bf16(x), 16 elements per thread ----
        size_t base = (size_t)(bid - 1088) * 4096 + (size_t)t * 16;
        float4 a0 = *(const float4*)(x + base);
        float4 a1 = *(const float4*)(x + base + 4);
        float4 a2 = *(const float4*)(x + base + 8);
        float4 a3 = *(const float4*)(x + base + 12);
        bf16x8 o0, o1;
        o0[0] = (bf16_t)a0.x; o0[1] = (bf16_t)a0.y; o0[2] = (bf16_t)a0.z; o0[3] = (bf16_t)a0.w;
        o0[4] = (bf16_t)a1.x; o0[5] = (bf16_t)a1.y; o0[6] = (bf16_t)a1.z; o0[7] = (bf16_t)a1.w;
        o1[0] = (bf16_t)a2.x; o1[1] = (bf16_t)a2.y; o1[2] = (bf16_t)a2.z; o1[3] = (bf16_t)a2.w;
        o1[4] = (bf16_t)a3.x; o1[5] = (bf16_t)a3.y; o1[6] = (bf16_t)a3.z; o1[7] = (bf16_t)a3.w;
        *(bf16x8*)(xb + base)     = o0;
        *(bf16x8*)(xb + base + 8) = o1;
        return;
    }

    if (bid < 64) {
        // ---- transpose ij_w1 fp32[k][n] -> bf16 Wt1[n][k] ----
        float (*tile)[33] = (float (*)[33])arena;
        int bx = bid & 7, by = bid >> 3;
        int tx = t & 31, ty = t >> 5;
        #pragma unroll
        for (int r = 0; r < 32; r += 8)
            tile[ty + r][tx] = ij_w1[(by * 32 + ty + r) * 256 + bx * 32 + tx];
        __syncthreads();
        #pragma unroll
        for (int r = 0; r < 32; r += 8)
            Wt1[(bx * 32 + ty + r) * 256 + by * 32 + tx] = (bf16_t)tile[tx][ty + r];
    } else if (bid < 320) {
        // ---- Mt[b][a] = sum_c ij_w2[a][c] * lin_w1[c][b] (bf16 [n][k]) ----
        float (*S)[33] = (float (*)[33])arena;
        int b = bid - 64;
        int cc = t & 31, abase = t >> 5;
        float acc = 0.f;
        for (int c0 = 0; c0 < 256; c0 += 32) {
            __syncthreads();
            #pragma unroll
            for (int r = 0; r < 32; ++r) {
                int a = r * 8 + abase;
                S[a][cc] = w2[a * 256 + c0 + cc];
            }
            __syncthreads();
            #pragma unroll 8
            for (int c2 = 0; c2 < 32; ++c2) {
                float wv = lw1[(c0 + c2) * 256 + b];   // uniform -> scalar
                acc += S[t][c2] * wv;
            }
        }
        Mt[(size_t)b * 256 + t] = (bf16_t)acc;
    } else if (bid < 576) {
        // ---- cvec[b] = ij_b2 @ lin_w1 + lin_b1 ----
        float* red = (float*)arena;
        int b = bid - 320;
        red[t] = b2[t] * lw1[t * 256 + b];
        __syncthreads();
        for (int s = 128; s > 0; s >>= 1) {
            if (t < s) red[t] += red[t + s];
            __syncthreads();
        }
        if (t == 0) cvec[b] = red[0] + lb1[b];
    } else {
        // ---- T2[v] = (cn_mlp(v) * beta) @ lin_w1, v = 0..511 ----
        float* t1 = (float*)arena;
        float* t2 = (float*)(arena + 1024);
        float* t3 = (float*)(arena + 2048);
        int v = bid - 576;
        float fv = (float)v;
        t1[t] = fmaxf(fv * cw1[t] + cb1[t], 0.f);
        __syncthreads();
        float s = cb2[t];
        for (int k = 0; k < 256; ++k) s += t1[k] * cw2[k * 256 + t];
        t2[t] = fmaxf(s, 0.f);
        __syncthreads();
        s = cb3[t];
        for (int k = 0; k < 256; ++k) s += t2[k] * cw3[k * 256 + t];
        t3[t] = s * beta[0];
        __syncthreads();
        s = 0.f;
        for (int k = 0; k < 256; ++k) s += t3[k] * lw1[k * 256 + t];
        T2[(size_t)v * 256 + t] = s;
    }
}

// ---------------- fused: 64-edge tile (B amortization), CN folded in ---------
// CN: all 32 nbr gathers issued at kernel top (drain under staging's vmcnt);
// shfl binary-searches run right after barrier 1 (va/vb die before acc is
// live -> lower peak VGPR), overlapped by co-resident blocks' GEMM phases.
__global__ __launch_bounds__(256, 3)
void fused_kernel(const bf16_t* __restrict__ xb, const int* __restrict__ tar,
                  const int* __restrict__ nbr,
                  const bf16_t* __restrict__ Wt1, const float* __restrict__ b1,
                  const bf16_t* __restrict__ Mt, const float* __restrict__ cvec,
                  const float* __restrict__ T2,
                  const float* __restrict__ w2, const float* __restrict__ b2s,
                  float* __restrict__ out) {
    __shared__ __align__(16) bf16_t X[64 * 256];   // A tile, then g tile
    __shared__ float rowacc[64];
    __shared__ int xcn_s[64];

    const int tid  = threadIdx.x;
    const int lane = tid & 63;
    const int wc   = tid >> 6;          // wave = col quarter 0..3
    const int quad = lane >> 4;
    const int l16  = lane & 15;
    const int e0   = blockIdx.x * 64;

    // ---- CN phase 1: ISSUE nbr gathers for this wave's 16 edges ----
    int va[16], vb[16];
    #pragma unroll
    for (int i = 0; i < 16; ++i) {
        int e = e0 + wc * 16 + i;
        int s = __builtin_amdgcn_readfirstlane(tar[e]);
        int d = __builtin_amdgcn_readfirstlane(tar[EE + e]);
        va[i] = nbr[(size_t)s * DDEG + lane];
        vb[i] = nbr[(size_t)d * DDEG + lane];
    }

    // ---- stage A = bf16(xi * xj), 4 threads/row, full K, swizzled writes ----
    {
        const int srow   = tid >> 2;
        const int skbase = (tid & 3) * 8;
        int e = e0 + srow;
        const bf16_t* xi = xb + (size_t)tar[e] * 256 + skbase;
        const bf16_t* xj = xb + (size_t)tar[EE + e] * 256 + skbase;
        bf16x8 ui[8], vj[8];
        #pragma unroll
        for (int kc = 0; kc < 8; ++kc) {
            ui[kc] = *(const bf16x8*)(xi + kc * 32);
            vj[kc] = *(const bf16x8*)(xj + kc * 32);
        }
        #pragma unroll
        for (int kc = 0; kc < 8; ++kc) {
            bf16x8 p;
            #pragma unroll
            for (int m = 0; m < 8; ++m)
                p[m] = (bf16_t)((float)ui[kc][m] * (float)vj[kc][m]);
            *(bf16x8*)&X[SWZ(srow, kc * 32 + skbase)] = p;
        }
    }

    __syncthreads();   // barrier 1: A staged (vmcnt(0) also landed va/vb)

    // ---- CN phase 2: binary searches, 2 edges packed per reduce ----
    // Per a-lane count = upper_bound - lower_bound over sorted vb (dup-correct);
    // per-lane counts <=64, wave sums <=4096 -> two 16-bit fields, no carry.
    #pragma unroll
    for (int p = 0; p < 8; ++p) {
        int cpk = 0;
        #pragma unroll
        for (int h = 0; h < 2; ++h) {
            int i = p * 2 + h;
            int lo = 0, hi = 0;
            #pragma unroll
            for (int st = 32; st; st >>= 1) {
                int bl = __shfl(vb[i], lo + st - 1, 64);
                int bh = __shfl(vb[i], hi + st - 1, 64);
                lo += (bl < va[i]) ? st : 0;
                hi += (bh <= va[i]) ? st : 0;
            }
            int b63 = __shfl(vb[i], 63, 64);      // count==64 correction
            lo += (b63 < va[i]) ? 1 : 0;
            hi += (b63 <= va[i]) ? 1 : 0;
            cpk += (hi - lo) << (16 * h);
        }
        #pragma unroll
        for (int off = 32; off; off >>= 1) cpk += __shfl_xor(cpk, off, 64);
        if (lane == 0) {
            int c0 = cpk & 0xffff, c1 = (int)((unsigned)cpk >> 16);
            xcn_s[wc * 16 + p * 2]     = c0 < 511 ? c0 : 511;
            xcn_s[wc * 16 + p * 2 + 1] = c1 < 511 ? c1 : 511;
        }
    }

    floatx4 acc[4][4];
    #pragma unroll
    for (int i = 0; i < 4; ++i)
        #pragma unroll
        for (int j = 0; j < 4; ++j)
            acc[i][j] = (floatx4){0.f, 0.f, 0.f, 0.f};

    // ---- GEMM1: A from LDS (swizzled), B direct from global (L2-hot) ----
    #pragma unroll 2
    for (int kc = 0; kc < 8; ++kc) {
        const int k0 = kc * 32 + quad * 8;
        bf16x8 af[4], bfr[4];
        #pragma unroll
        for (int j = 0; j < 4; ++j)
            bfr[j] = *(const bf16x8*)(Wt1 + (size_t)(wc * 64 + j * 16 + l16) * 256 + k0);
        #pragma unroll
        for (int i = 0; i < 4; ++i)
            af[i] = *(const bf16x8*)(&X[SWZ(i * 16 + l16, k0)]);
        #pragma unroll
        for (int i = 0; i < 4; ++i)
            #pragma unroll
            for (int j = 0; j < 4; ++j)
                acc[i][j] = __builtin_amdgcn_mfma_f32_16x16x32_bf16(
                                af[i], bfr[j], acc[i][j], 0, 0, 0);
    }

    __syncthreads();   // barrier 2: all A reads done, X reusable for g

    // ---- epilogue 1: g tile -> X (bf16, swizzled) ----
    #pragma unroll
    for (int j = 0; j < 4; ++j) {
        int col  = wc * 64 + j * 16 + l16;
        float bv = b1[col];
        #pragma unroll
        for (int i = 0; i < 4; ++i)
            #pragma unroll
            for (int r = 0; r < 4; ++r) {
                int row = i * 16 + quad * 4 + r;
                X[SWZ(row, col)] = (bf16_t)fmaxf(acc[i][j][r] + bv, 0.f);
            }
    }
    #pragma unroll
    for (int i = 0; i < 4; ++i)
        #pragma unroll
        for (int j = 0; j < 4; ++j)
            acc[i][j] = (floatx4){0.f, 0.f, 0.f, 0.f};
    if (tid < 64) rowacc[tid] = 0.f;

    __syncthreads();   // barrier 3: g + xcn_s visible, rowacc init

    // ---- GEMM2: g @ M; A from LDS (swizzled), B direct from global ----
    #pragma unroll 2
    for (int kc = 0; kc < 8; ++kc) {
        const int k0 = kc * 32 + quad * 8;
        bf16x8 af[4], bfr[4];
        #pragma unroll
        for (int j = 0; j < 4; ++j)
            bfr[j] = *(const bf16x8*)(Mt + (size_t)(wc * 64 + j * 16 + l16) * 256 + k0);
        #pragma unroll
        for (int i = 0; i < 4; ++i)
            af[i] = *(const bf16x8*)(&X[SWZ(i * 16 + l16, k0)]);
        #pragma unroll
        for (int i = 0; i < 4; ++i)
            #pragma unroll
            for (int j = 0; j < 4; ++j)
                acc[i][j] = __builtin_amdgcn_mfma_f32_16x16x32_bf16(
                                af[i], bfr[j], acc[i][j], 0, 0, 0);
    }

    // ---- final epilogue: +cvec +T2[xcn], relu, dot w2, row-reduce ----
    int xv[16];
    #pragma unroll
    for (int i = 0; i < 4; ++i)
        #pragma unroll
        for (int r = 0; r < 4; ++r)
            xv[i * 4 + r] = xcn_s[i * 16 + quad * 4 + r];

    float pr[16];
    #pragma unroll
    for (int t = 0; t < 16; ++t) pr[t] = 0.f;
    #pragma unroll
    for (int j = 0; j < 4; ++j) {
        int col  = wc * 64 + j * 16 + l16;
        float cv = cvec[col];
        float wv = w2[col];
        #pragma unroll
        for (int i = 0; i < 4; ++i)
            #pragma unroll
            for (int r = 0; r < 4; ++r) {
                float t2v = T2[(size_t)xv[i * 4 + r] * 256 + col];
                float v = fmaxf(acc[i][j][r] + cv + t2v, 0.f);
                pr[i * 4 + r] += v * wv;
            }
    }
    #pragma unroll
    for (int off = 1; off < 16; off <<= 1)
        #pragma unroll
        for (int t = 0; t < 16; ++t)
            pr[t] += __shfl_xor(pr[t], off, 64);
    if (l16 == 0) {
        #pragma unroll
        for (int i = 0; i < 4; ++i)
            #pragma unroll
            for (int r = 0; r < 4; ++r)
                atomicAdd(&rowacc[i * 16 + quad * 4 + r], pr[i * 4 + r]);
    }
    __syncthreads();
    if (tid < 64) out[e0 + tid] = rowacc[tid] + b2s[0];
}

extern "C" void kernel_launch(void* const* d_in, const int* in_sizes, int n_in,
                              void* d_out, int out_size, void* d_ws, size_t ws_size,
                              hipStream_t stream) {
    const float* x      = (const float*)d_in[0];
    const int*   nbr    = (const int*)  d_in[1];
    const int*   tar    = (const int*)  d_in[2];
    const float* beta   = (const float*)d_in[3];
    const float* cn_w1  = (const float*)d_in[4];
    const float* cn_b1  = (const float*)d_in[5];
    const float* cn_w2  = (const float*)d_in[6];
    const float* cn_b2  = (const float*)d_in[7];
    const float* cn_w3  = (const float*)d_in[8];
    const float* cn_b3  = (const float*)d_in[9];
    const float* ij_w1  = (const float*)d_in[10];
    const float* ij_b1  = (const float*)d_in[11];
    const float* ij_w2  = (const float*)d_in[12];
    const float* ij_b2  = (const float*)d_in[13];
    const float* lin_w1 = (const float*)d_in[14];
    const float* lin_b1 = (const float*)d_in[15];
    const float* lin_w2 = (const float*)d_in[16];
    const float* lin_b2 = (const float*)d_in[17];

    char* ws = (char*)d_ws;
    float*  T2    = (float*) (ws + 0);        // 512*256*4  = 524288
    bf16_t* Wt1   = (bf16_t*)(ws + 1048576);  // 256*256*2  = 131072
    bf16_t* Mt    = (bf16_t*)(ws + 1179648);  // 256*256*2  = 131072
    float*  cvec  = (float*) (ws + 1310720);  // 256*4 -> pad to 1312768
    bf16_t* xb    = (bf16_t*)(ws + 1312768);  // 100000*256*2 = 51.2 MB

    prep_kernel<<<1088 + 6250, 256, 0, stream>>>(
        x, xb, ij_w1, Wt1, ij_w2, lin_w1, Mt,
        ij_b2, lin_b1, cvec,
        cn_w1, cn_b1, cn_w2, cn_b2, cn_w3, cn_b3, beta, T2);
    fused_kernel<<<EE / 64, 256, 0, stream>>>(xb, tar, nbr, Wt1, ij_b1, Mt, cvec,
                                              T2, lin_w2, lin_b2,
                                              (float*)d_out);
}